// Round 1
// baseline (1435.199 us; speedup 1.0000x reference)
//
#include <hip/hip_runtime.h>
#include <math.h>

#define HH 96
#define WW 96
#define HW 9216
#define CIN 128
#define COUT 256

// ---------------- prep kernels ----------------

// offmask layout: [B][27][H][W]; ch 0..17 = offset (pre-bias-added), 18..26 = mask logits
__global__ void k_init(float* __restrict__ om, const float* __restrict__ offb,
                       const float* __restrict__ modb) {
  int i = blockIdx.x * 256 + threadIdx.x;
  if (i >= 4 * 27 * HW) return;
  int co = (i / HW) % 27;
  om[i] = (co < 18) ? offb[co] : modb[co - 18];
}

// wA[ck][28]: ck = c*9 + (ky*3+kx); col co<18 from offset_w, 18..26 from mod_w; col27 = pad
__global__ void k_build_wA(float* __restrict__ wA, const float* __restrict__ offw,
                           const float* __restrict__ modw) {
  int i = blockIdx.x * 256 + threadIdx.x;
  if (i >= 1152 * 27) return;
  int ck = i / 27, co = i % 27;
  float v = (co < 18) ? offw[co * 1152 + ck] : modw[(co - 18) * 1152 + ck];
  wA[ck * 28 + co] = v;
}

// wT[ck][256] from weight[o][ck] (o fastest in wT rows -> coalesced phase-B reads)
__global__ void k_build_wT(float* __restrict__ wT, const float* __restrict__ w) {
  int i = blockIdx.x * 256 + threadIdx.x;
  if (i >= COUT * 1152) return;
  int o = i / 1152, ck = i % 1152;
  wT[ck * 256 + o] = w[i];
}

// ---------------- offset/mask conv (split-K over C, atomic accumulate) ----------------
// grid: 4(b) x 24(row-quads) x 8(c-chunks of 16) = 768 blocks, 192 threads
// thread: sub = t/96 in {0,1}, wo = t%96; handles rows r0=rg*4+sub*2 and r0+1, all 27 couts
__global__ __launch_bounds__(192) void k_conv(const float* __restrict__ x,
                                              const float* __restrict__ wA,
                                              float* __restrict__ om) {
  int bid = blockIdx.x;
  int ch = bid & 7;
  int rg = (bid >> 3) % 24;
  int b  = bid / 192;
  int t = threadIdx.x;
  int sub = t / 96, wo = t % 96;
  int r0 = rg * 4 + sub * 2;

  float a0[27], a1[27];
#pragma unroll
  for (int i = 0; i < 27; ++i) { a0[i] = 0.f; a1[i] = 0.f; }

  for (int cl = 0; cl < 16; ++cl) {
    int c = ch * 16 + cl;
    const float* xb = x + (size_t)(b * CIN + c) * HW;
#pragma unroll
    for (int ky = 0; ky < 3; ++ky) {
      int ya = r0 + ky - 1;
      int yb2 = ya + 1;
      bool oka = (unsigned)ya < 96u;
      bool okb = (unsigned)yb2 < 96u;
      int yac = min(max(ya, 0), 95), ybc = min(max(yb2, 0), 95);
#pragma unroll
      for (int kx = 0; kx < 3; ++kx) {
        int xx = wo + kx - 1;
        bool okx = (unsigned)xx < 96u;
        int xxc = min(max(xx, 0), 95);
        float va = xb[yac * 96 + xxc];
        float vb = xb[ybc * 96 + xxc];
        va = (oka && okx) ? va : 0.f;
        vb = (okb && okx) ? vb : 0.f;
        const float4* w4 = (const float4*)(wA + (c * 9 + ky * 3 + kx) * 28);
#pragma unroll
        for (int q = 0; q < 7; ++q) {
          float4 wv = w4[q];
          int base = 4 * q;
          a0[base] += wv.x * va; a1[base] += wv.x * vb;
          if (base + 1 < 27) { a0[base + 1] += wv.y * va; a1[base + 1] += wv.y * vb; }
          if (base + 2 < 27) { a0[base + 2] += wv.z * va; a1[base + 2] += wv.z * vb; }
          if (base + 3 < 27) { a0[base + 3] += wv.w * va; a1[base + 3] += wv.w * vb; }
        }
      }
    }
  }
  float* dst = om + (size_t)b * 27 * HW + r0 * 96 + wo;
#pragma unroll
  for (int co = 0; co < 27; ++co) {
    atomicAdd(dst + co * HW, a0[co]);
    atomicAdd(dst + co * HW + 96, a1[co]);
  }
}

__global__ void k_sig(float* __restrict__ om) {
  int i = blockIdx.x * 256 + threadIdx.x;
  if (i >= 4 * 9 * HW) return;
  int b = i / (9 * HW);
  int r = i % (9 * HW);
  float* p = om + (size_t)b * 27 * HW + 18 * HW + r;
  float v = *p;
  *p = 1.f / (1.f + expf(-v));
}

// ---------------- main deformable conv ----------------
// block = 8 pixels (one row segment), 256 threads.
// phase A: sample val[p][c*9+k] (mask folded into bilinear weights) -> LDS (row pad 1160)
// phase B: 32 o-lanes x 8 p-groups, 8 output channels per thread, wT float4 reads
__global__ __launch_bounds__(256) void k_main(const float* __restrict__ x,
                                              const float* __restrict__ wT,
                                              const float* __restrict__ bias,
                                              const float* __restrict__ om,
                                              float* __restrict__ out) {
  __shared__ __align__(16) float vs[8 * 1160];
  int bid = blockIdx.x;
  int b = bid / 1152;
  int pos0 = (bid % 1152) * 8;
  int ho = pos0 / 96, wo0 = pos0 % 96;
  int t = threadIdx.x;
  {
    int p = t & 7, cg = t >> 3;
    int wo = wo0 + p;
    const float* omp = om + (size_t)b * 27 * HW + ho * 96 + wo;
    const float* xb0 = x + (size_t)b * CIN * HW;
    for (int k = 0; k < 9; ++k) {
      float dy = omp[(2 * k) * HW];
      float dx = omp[(2 * k + 1) * HW];
      float m  = omp[(18 + k) * HW];
      float py = (float)(ho - 1 + k / 3) + dy;
      float px = (float)(wo - 1 + k % 3) + dx;
      float fy = floorf(py), fx = floorf(px);
      int y0 = (int)fy, x0 = (int)fx;
      float ly = py - fy, lx = px - fx;
      float w00 = (1.f - ly) * (1.f - lx), w01 = (1.f - ly) * lx;
      float w10 = ly * (1.f - lx),         w11 = ly * lx;
      bool vy0 = (unsigned)y0 < 96u, vy1 = (unsigned)(y0 + 1) < 96u;
      bool vx0 = (unsigned)x0 < 96u, vx1 = (unsigned)(x0 + 1) < 96u;
      w00 = (vy0 && vx0) ? w00 * m : 0.f;
      w01 = (vy0 && vx1) ? w01 * m : 0.f;
      w10 = (vy1 && vx0) ? w10 * m : 0.f;
      w11 = (vy1 && vx1) ? w11 * m : 0.f;
      int y0c = min(max(y0, 0), 95), y1c = min(max(y0 + 1, 0), 95);
      int x0c = min(max(x0, 0), 95), x1c = min(max(x0 + 1, 0), 95);
      int o00 = y0c * 96 + x0c, o01 = y0c * 96 + x1c;
      int o10 = y1c * 96 + x0c, o11 = y1c * 96 + x1c;
#pragma unroll
      for (int i = 0; i < 4; ++i) {
        int c = cg + 32 * i;
        const float* xb = xb0 + (size_t)c * HW;
        float v = w00 * xb[o00] + w01 * xb[o01] + w10 * xb[o10] + w11 * xb[o11];
        vs[p * 1160 + c * 9 + k] = v;
      }
    }
  }
  __syncthreads();

  int j = t & 31, p = t >> 5;
  float acc[8];
#pragma unroll
  for (int i = 0; i < 8; ++i) acc[i] = 0.f;
  const float4* vrow = (const float4*)(vs + p * 1160);
  const float* wbase = wT + j * 8;
  for (int q = 0; q < 288; ++q) {
    float4 v4 = vrow[q];
    const float* wrow = wbase + q * 1024;
#pragma unroll
    for (int r = 0; r < 4; ++r) {
      float v = (r == 0) ? v4.x : (r == 1) ? v4.y : (r == 2) ? v4.z : v4.w;
      float4 wa = *(const float4*)(wrow + r * 256);
      float4 wb = *(const float4*)(wrow + r * 256 + 4);
      acc[0] += wa.x * v; acc[1] += wa.y * v; acc[2] += wa.z * v; acc[3] += wa.w * v;
      acc[4] += wb.x * v; acc[5] += wb.y * v; acc[6] += wb.z * v; acc[7] += wb.w * v;
    }
  }
  int wo = wo0 + p;
  int o0 = j * 8;
  float4 bb0 = *(const float4*)(bias + o0);
  float4 bb1 = *(const float4*)(bias + o0 + 4);
  float* op = out + ((size_t)(b * COUT + o0) * 96 + ho) * 96 + wo;
  op[0 * HW] = acc[0] + bb0.x;
  op[1 * HW] = acc[1] + bb0.y;
  op[2 * HW] = acc[2] + bb0.z;
  op[3 * HW] = acc[3] + bb0.w;
  op[4 * HW] = acc[4] + bb1.x;
  op[5 * HW] = acc[5] + bb1.y;
  op[6 * HW] = acc[6] + bb1.z;
  op[7 * HW] = acc[7] + bb1.w;
}

extern "C" void kernel_launch(void* const* d_in, const int* in_sizes, int n_in,
                              void* d_out, int out_size, void* d_ws, size_t ws_size,
                              hipStream_t stream) {
  const float* x      = (const float*)d_in[0];
  const float* weight = (const float*)d_in[1];
  const float* bias   = (const float*)d_in[2];
  const float* offw   = (const float*)d_in[3];
  const float* offb   = (const float*)d_in[4];
  const float* modw   = (const float*)d_in[5];
  const float* modb   = (const float*)d_in[6];
  float* out = (float*)d_out;
  float* ws = (float*)d_ws;

  float* offmask = ws;                       // 995328 floats
  float* wT      = ws + 995328;              // 294912 floats
  float* wA      = ws + 995328 + 294912;     // 32256 floats
  // total ws use: 5,289,984 bytes

  k_init<<<3888, 256, 0, stream>>>(offmask, offb, modb);
  k_build_wA<<<122, 256, 0, stream>>>(wA, offw, modw);
  k_build_wT<<<1152, 256, 0, stream>>>(wT, weight);
  k_conv<<<768, 192, 0, stream>>>(x, wA, offmask);
  k_sig<<<1296, 256, 0, stream>>>(offmask);
  k_main<<<4608, 256, 0, stream>>>(x, wT, bias, offmask, out);
}

// Round 2
// 285.152 us; speedup vs baseline: 5.0331x; 5.0331x over previous
//
#include <hip/hip_runtime.h>
#include <math.h>

#define HH 96
#define WW 96
#define HW 9216
#define CIN 128
#define COUT 256

typedef __attribute__((ext_vector_type(8))) short short8;
typedef __attribute__((ext_vector_type(4))) short short4v;
typedef __attribute__((ext_vector_type(4))) float f32x4;

static __device__ __forceinline__ unsigned short f2bf(float f) {
  union { float f; unsigned u; } v; v.f = f;
  unsigned r = v.u + 0x7FFF + ((v.u >> 16) & 1);
  return (unsigned short)(r >> 16);
}

// ---------------- prep kernels ----------------

// offmask layout: [B][27][H][W]; ch 0..17 = offset (bias-init), 18..26 = mask logits
__global__ void k_init(float* __restrict__ om, const float* __restrict__ offb,
                       const float* __restrict__ modb) {
  int i = blockIdx.x * 256 + threadIdx.x;
  if (i >= 4 * 27 * HW) return;
  int co = (i / HW) % 27;
  om[i] = (co < 18) ? offb[co] : modb[co - 18];
}

// wA[ck][28]: ck = c*9 + (ky*3+kx); col co<18 from offset_w, 18..26 from mod_w
__global__ void k_build_wA(float* __restrict__ wA, const float* __restrict__ offw,
                           const float* __restrict__ modw) {
  int i = blockIdx.x * 256 + threadIdx.x;
  if (i >= 1152 * 27) return;
  int ck = i / 27, co = i % 27;
  float v = (co < 18) ? offw[co * 1152 + ck] : modw[(co - 18) * 1152 + ck];
  wA[ck * 28 + co] = v;
}

// wTt[n][kk] bf16, kk = kpos*128 + c, from weight[n][c][ky][kx]
__global__ void k_wtb(unsigned short* __restrict__ wTt, const float* __restrict__ wgt) {
  int i = blockIdx.x * 256 + threadIdx.x;
  if (i >= COUT * 1152) return;
  int n = i / 1152, r = i % 1152, k = r / 128, c = r % 128;
  wTt[i] = f2bf(wgt[n * 1152 + c * 9 + k]);
}

// x NCHW -> xT NHWC (LDS-tiled transpose)
__global__ __launch_bounds__(256) void k_xt(const float* __restrict__ x,
                                            float* __restrict__ xT) {
  __shared__ float tile[32][129];
  int bid = blockIdx.x;             // b*288 + h*3 + wseg
  int wseg = bid % 3, h = (bid / 3) % 96, b = bid / 288;
  int t = threadIdx.x;
  int wl = t & 31, cg = t >> 5;
  const float* xp = x + ((size_t)(b * 128 + cg) * 96 + h) * 96 + wseg * 32 + wl;
#pragma unroll
  for (int i = 0; i < 16; ++i)
    tile[wl][cg + 8 * i] = xp[(size_t)8 * i * HW];
  __syncthreads();
  int cl = t & 127, wg = t >> 7;
  float* op = xT + (((size_t)(b * 96 + h) * 96) + wseg * 32) * 128 + cl;
#pragma unroll
  for (int i = 0; i < 16; ++i)
    op[(size_t)(wg + 2 * i) * 128] = tile[wg + 2 * i][cl];
}

// ---------------- offset/mask conv (split-K over C, atomic accumulate) ----------------
__global__ __launch_bounds__(192) void k_conv(const float* __restrict__ x,
                                              const float* __restrict__ wA,
                                              float* __restrict__ om) {
  int bid = blockIdx.x;
  int ch = bid & 7;
  int rg = (bid >> 3) % 24;
  int b  = bid / 192;
  int t = threadIdx.x;
  int sub = t / 96, wo = t % 96;
  int r0 = rg * 4 + sub * 2;

  float a0[27], a1[27];
#pragma unroll
  for (int i = 0; i < 27; ++i) { a0[i] = 0.f; a1[i] = 0.f; }

  for (int cl = 0; cl < 16; ++cl) {
    int c = ch * 16 + cl;
    const float* xb = x + (size_t)(b * CIN + c) * HW;
#pragma unroll
    for (int ky = 0; ky < 3; ++ky) {
      int ya = r0 + ky - 1;
      int yb2 = ya + 1;
      bool oka = (unsigned)ya < 96u;
      bool okb = (unsigned)yb2 < 96u;
      int yac = min(max(ya, 0), 95), ybc = min(max(yb2, 0), 95);
#pragma unroll
      for (int kx = 0; kx < 3; ++kx) {
        int xx = wo + kx - 1;
        bool okx = (unsigned)xx < 96u;
        int xxc = min(max(xx, 0), 95);
        float va = xb[yac * 96 + xxc];
        float vb = xb[ybc * 96 + xxc];
        va = (oka && okx) ? va : 0.f;
        vb = (okb && okx) ? vb : 0.f;
        const float4* w4 = (const float4*)(wA + (c * 9 + ky * 3 + kx) * 28);
#pragma unroll
        for (int q = 0; q < 7; ++q) {
          float4 wv = w4[q];
          int base = 4 * q;
          a0[base] += wv.x * va; a1[base] += wv.x * vb;
          if (base + 1 < 27) { a0[base + 1] += wv.y * va; a1[base + 1] += wv.y * vb; }
          if (base + 2 < 27) { a0[base + 2] += wv.z * va; a1[base + 2] += wv.z * vb; }
          if (base + 3 < 27) { a0[base + 3] += wv.w * va; a1[base + 3] += wv.w * vb; }
        }
      }
    }
  }
  float* dst = om + (size_t)b * 27 * HW + r0 * 96 + wo;
#pragma unroll
  for (int co = 0; co < 27; ++co) {
    atomicAdd(dst + co * HW, a0[co]);
    atomicAdd(dst + co * HW + 96, a1[co]);
  }
}

__global__ void k_sig(float* __restrict__ om) {
  int i = blockIdx.x * 256 + threadIdx.x;
  if (i >= 4 * 9 * HW) return;
  int b = i / (9 * HW);
  int r = i % (9 * HW);
  float* p = om + (size_t)b * 27 * HW + 18 * HW + r;
  float v = *p;
  *p = 1.f / (1.f + expf(-v));
}

// ---------------- main deformable conv: MFMA GEMM ----------------
// 576 blocks x 256 thr. M-tile 64 px, N = 256, K = 9 taps x 128 c (kk = kpos*128+c).
// Per tap: corner geometry once (64 px), then 2 chunks of BK=64:
//   stage A (sampled vals, bf16) + B (wTt slice, bf16) into padded LDS, 2x16 mfma.
__global__ __launch_bounds__(256) void k_mfma(const float* __restrict__ xT,
                                              const unsigned short* __restrict__ wTt,
                                              const float* __restrict__ bias,
                                              const float* __restrict__ om,
                                              float* __restrict__ out) {
  __shared__ __align__(16) unsigned short Ab[64 * 72];    // 9216 B
  __shared__ __align__(16) unsigned short Bb[256 * 72];   // 36864 B
  __shared__ __align__(16) float cw[64 * 8];              // 2048 B

  int t = threadIdx.x;
  int l = t & 63;
  int w = t >> 6;
  int lm = l & 15, lq = l >> 4;
  int bid = blockIdx.x;
  int pix0 = bid * 64;
  int b = pix0 / HW;
  int pos0 = pix0 % HW;

  f32x4 acc[4][4];
#pragma unroll
  for (int i = 0; i < 4; ++i)
#pragma unroll
    for (int j = 0; j < 4; ++j)
      acc[i][j] = (f32x4){0.f, 0.f, 0.f, 0.f};

  for (int kpos = 0; kpos < 9; ++kpos) {
    if (t < 64) {
      int pos = pos0 + t;
      int ho = pos / 96, wo = pos % 96;
      const float* omp = om + (size_t)b * 27 * HW + pos;
      float dy = omp[(size_t)(2 * kpos) * HW];
      float dx = omp[(size_t)(2 * kpos + 1) * HW];
      float mk = omp[(size_t)(18 + kpos) * HW];
      float py = (float)(ho - 1 + kpos / 3) + dy;
      float px = (float)(wo - 1 + kpos % 3) + dx;
      float fy = floorf(py), fx = floorf(px);
      int y0 = (int)fy, x0 = (int)fx;
      float ly = py - fy, lx = px - fx;
      float w00 = (1.f - ly) * (1.f - lx), w01 = (1.f - ly) * lx;
      float w10 = ly * (1.f - lx),         w11 = ly * lx;
      bool vy0 = (unsigned)y0 < 96u, vy1 = (unsigned)(y0 + 1) < 96u;
      bool vx0 = (unsigned)x0 < 96u, vx1 = (unsigned)(x0 + 1) < 96u;
      w00 = (vy0 && vx0) ? w00 * mk : 0.f;
      w01 = (vy0 && vx1) ? w01 * mk : 0.f;
      w10 = (vy1 && vx0) ? w10 * mk : 0.f;
      w11 = (vy1 && vx1) ? w11 * mk : 0.f;
      int y0c = min(max(y0, 0), 95), y1c = min(max(y0 + 1, 0), 95);
      int x0c = min(max(x0, 0), 95), x1c = min(max(x0 + 1, 0), 95);
      int base = b * HW;
      int o00 = (base + y0c * 96 + x0c) * 128;
      int o01 = (base + y0c * 96 + x1c) * 128;
      int o10 = (base + y1c * 96 + x0c) * 128;
      int o11 = (base + y1c * 96 + x1c) * 128;
      cw[t * 8 + 0] = w00; cw[t * 8 + 1] = w01;
      cw[t * 8 + 2] = w10; cw[t * 8 + 3] = w11;
      cw[t * 8 + 4] = __int_as_float(o00); cw[t * 8 + 5] = __int_as_float(o01);
      cw[t * 8 + 6] = __int_as_float(o10); cw[t * 8 + 7] = __int_as_float(o11);
    }
    __syncthreads();
#pragma unroll
    for (int half = 0; half < 2; ++half) {
      int c0 = half * 64;
      // ---- stage B: wTt rows n, k-slice [kpos*128+c0, +64) -> Bb[n][k] pad 72
      {
        const unsigned short* src = wTt + (size_t)(t >> 3) * 1152 + kpos * 128 + c0 + (t & 7) * 8;
        unsigned short* dst = Bb + (t >> 3) * 72 + (t & 7) * 8;
#pragma unroll
        for (int pp = 0; pp < 8; ++pp)
          *(short8*)(dst + pp * 32 * 72) = *(const short8*)(src + (size_t)pp * 32 * 1152);
      }
      // ---- stage A: sample 64 px x 64 c -> Ab[px][k] pad 72
      {
        int ci = (t & 15) * 4;
#pragma unroll
        for (int pass = 0; pass < 4; ++pass) {
          int pxi = pass * 16 + (t >> 4);
          f32x4 cwa = *(f32x4*)(cw + pxi * 8);
          f32x4 cwb = *(f32x4*)(cw + pxi * 8 + 4);
          int cc = c0 + ci;
          const f32x4* p00 = (const f32x4*)(xT + __float_as_int(cwb[0]) + cc);
          const f32x4* p01 = (const f32x4*)(xT + __float_as_int(cwb[1]) + cc);
          const f32x4* p10 = (const f32x4*)(xT + __float_as_int(cwb[2]) + cc);
          const f32x4* p11 = (const f32x4*)(xT + __float_as_int(cwb[3]) + cc);
          f32x4 v = cwa[0] * (*p00) + cwa[1] * (*p01) + cwa[2] * (*p10) + cwa[3] * (*p11);
          short4v s;
          s[0] = (short)f2bf(v[0]); s[1] = (short)f2bf(v[1]);
          s[2] = (short)f2bf(v[2]); s[3] = (short)f2bf(v[3]);
          *(short4v*)(Ab + pxi * 72 + ci) = s;
        }
      }
      __syncthreads();
      // ---- MFMA
#pragma unroll
      for (int ks = 0; ks < 2; ++ks) {
        short8 af[4], bf[4];
#pragma unroll
        for (int mt = 0; mt < 4; ++mt)
          af[mt] = *(short8*)(Ab + (mt * 16 + lm) * 72 + ks * 32 + lq * 8);
#pragma unroll
        for (int nt = 0; nt < 4; ++nt)
          bf[nt] = *(short8*)(Bb + (w * 64 + nt * 16 + lm) * 72 + ks * 32 + lq * 8);
#pragma unroll
        for (int mt = 0; mt < 4; ++mt)
#pragma unroll
          for (int nt = 0; nt < 4; ++nt)
            acc[mt][nt] = __builtin_amdgcn_mfma_f32_16x16x32_bf16(af[mt], bf[nt], acc[mt][nt], 0, 0, 0);
      }
      __syncthreads();
    }
  }

  // ---- epilogue: per-wave LDS transpose -> coalesced stores
  float bias_v[4];
#pragma unroll
  for (int nt = 0; nt < 4; ++nt) bias_v[nt] = bias[w * 64 + nt * 16 + lm];
  float* ez = (float*)Bb + w * 1088;   // 64*17 floats per wave zone
#pragma unroll
  for (int nt = 0; nt < 4; ++nt) {
#pragma unroll
    for (int mt = 0; mt < 4; ++mt)
#pragma unroll
      for (int r = 0; r < 4; ++r)
        ez[(mt * 16 + lq * 4 + r) * 17 + lm] = acc[mt][nt][r] + bias_v[nt];
    __syncthreads();
    float* ob = out + ((size_t)(b * COUT + w * 64 + nt * 16)) * HW + pos0;
#pragma unroll
    for (int j = 0; j < 16; ++j)
      ob[(size_t)j * HW + l] = ez[l * 17 + j];
    __syncthreads();
  }
}

extern "C" void kernel_launch(void* const* d_in, const int* in_sizes, int n_in,
                              void* d_out, int out_size, void* d_ws, size_t ws_size,
                              hipStream_t stream) {
  const float* x      = (const float*)d_in[0];
  const float* weight = (const float*)d_in[1];
  const float* bias   = (const float*)d_in[2];
  const float* offw   = (const float*)d_in[3];
  const float* offb   = (const float*)d_in[4];
  const float* modw   = (const float*)d_in[5];
  const float* modb   = (const float*)d_in[6];
  float* out = (float*)d_out;
  float* ws = (float*)d_ws;

  float* offmask = ws;                               // 995328 f
  float* wA      = ws + 995328;                      // 32256 f
  float* xT      = ws + 995328 + 32256;              // 4718592 f
  unsigned short* wTt = (unsigned short*)(ws + 995328 + 32256 + 4718592); // 294912 us
  // total ws use ~23.6 MB

  k_init<<<3888, 256, 0, stream>>>(offmask, offb, modb);
  k_build_wA<<<122, 256, 0, stream>>>(wA, offw, modw);
  k_wtb<<<1152, 256, 0, stream>>>(wTt, weight);
  k_xt<<<1152, 256, 0, stream>>>(x, xT);
  k_conv<<<768, 192, 0, stream>>>(x, wA, offmask);
  k_sig<<<1296, 256, 0, stream>>>(offmask);
  k_mfma<<<576, 256, 0, stream>>>(xT, wTt, bias, offmask, out);
}

// Round 3
// 207.441 us; speedup vs baseline: 6.9186x; 1.3746x over previous
//
#include <hip/hip_runtime.h>
#include <math.h>

#define HH 96
#define WW 96
#define HW 9216
#define CIN 128
#define COUT 256

typedef __attribute__((ext_vector_type(8))) short short8;
typedef __attribute__((ext_vector_type(4))) float f32x4;

static __device__ __forceinline__ unsigned short f2bf(float f) {
  union { float f; unsigned u; } v; v.f = f;
  unsigned r = v.u + 0x7FFF + ((v.u >> 16) & 1);
  return (unsigned short)(r >> 16);
}
static __device__ __forceinline__ float bflo(unsigned u) {
  union { unsigned u; float f; } v; v.u = u << 16; return v.f;
}
static __device__ __forceinline__ float bfhi(unsigned u) {
  union { unsigned u; float f; } v; v.u = u & 0xffff0000u; return v.f;
}

// ---------------- prep kernels ----------------

// x NCHW fp32 -> xTb NHWC bf16
__global__ __launch_bounds__(256) void k_xtb(const float* __restrict__ x,
                                             unsigned short* __restrict__ xTb) {
  __shared__ float tile[32][129];
  int bid = blockIdx.x;             // b*288 + h*3 + wseg
  int wseg = bid % 3, h = (bid / 3) % 96, b = bid / 288;
  int t = threadIdx.x;
  int wl = t & 31, cg = t >> 5;
  const float* xp = x + ((size_t)(b * 128 + cg) * 96 + h) * 96 + wseg * 32 + wl;
#pragma unroll
  for (int i = 0; i < 16; ++i)
    tile[wl][cg + 8 * i] = xp[(size_t)8 * i * HW];
  __syncthreads();
  int cl = t & 127, wg = t >> 7;
  unsigned short* op = xTb + (((size_t)(b * 96 + h) * 96) + wseg * 32) * 128 + cl;
#pragma unroll
  for (int i = 0; i < 16; ++i)
    op[(size_t)(wg + 2 * i) * 128] = f2bf(tile[wg + 2 * i][cl]);
}

// wAb[32][1152] bf16, kk = kpos*128+c; n<18 offset_w, 18..26 mod_w, 27..31 zero
__global__ void k_wab(unsigned short* __restrict__ wAb, const float* __restrict__ offw,
                      const float* __restrict__ modw) {
  int i = blockIdx.x * 256 + threadIdx.x;
  if (i >= 32 * 1152) return;
  int n = i / 1152, r = i % 1152, kpos = r / 128, c = r % 128;
  float v = 0.f;
  if (n < 18) v = offw[n * 1152 + c * 9 + kpos];
  else if (n < 27) v = modw[(n - 18) * 1152 + c * 9 + kpos];
  wAb[i] = f2bf(v);
}

// wTt[n][kk] bf16, kk = kpos*128 + c, from weight[n][c][ky][kx]
__global__ void k_wtb(unsigned short* __restrict__ wTt, const float* __restrict__ wgt) {
  int i = blockIdx.x * 256 + threadIdx.x;
  if (i >= COUT * 1152) return;
  int n = i / 1152, r = i % 1152, kpos = r / 128, c = r % 128;
  wTt[i] = f2bf(wgt[n * 1152 + c * 9 + kpos]);
}

// ---------------- offset/mask conv via MFMA ----------------
// 144 blocks x 256 thr. M-tile 256 px (wave owns 64), N=32 (27 used), K=18x64.
// Epilogue: bias add; sigmoid for mask channels; write offmask [B][27][HW] fp32.
__global__ __launch_bounds__(256) void k_offconv(const unsigned short* __restrict__ xTb,
                                                 const unsigned short* __restrict__ wAb,
                                                 const float* __restrict__ offb,
                                                 const float* __restrict__ modb,
                                                 float* __restrict__ om) {
  __shared__ __align__(16) unsigned short Ab2[256 * 72];  // 36864 B
  __shared__ __align__(16) unsigned short Bb2[32 * 72];   // 4608 B

  int t = threadIdx.x;
  int l = t & 63;
  int w = t >> 6;
  int lm = l & 15, lq = l >> 4;
  int pix0 = blockIdx.x * 256;
  int b = pix0 / HW;
  int posim0 = pix0 % HW;

  f32x4 acc[4][2];
#pragma unroll
  for (int i = 0; i < 4; ++i)
#pragma unroll
    for (int j = 0; j < 2; ++j)
      acc[i][j] = (f32x4){0.f, 0.f, 0.f, 0.f};

  int pos = pix0 + t;
  int h = (pos % HW) / 96, wo = pos % 96;

  for (int kpos = 0; kpos < 9; ++kpos) {
    int dyr = kpos / 3 - 1, dxr = kpos % 3 - 1;
    bool valid = ((unsigned)(h + dyr) < 96u) && ((unsigned)(wo + dxr) < 96u);
    const unsigned short* srow = xTb + (size_t)(pos + dyr * 96 + dxr) * 128;
#pragma unroll
    for (int half = 0; half < 2; ++half) {
      int c0 = half * 64;
      __syncthreads();
      // stage B: 32 rows x 64 k
      *(short8*)(Bb2 + (t >> 3) * 72 + (t & 7) * 8) =
          *(const short8*)(wAb + (size_t)(t >> 3) * 1152 + kpos * 128 + c0 + (t & 7) * 8);
      // stage A: thread t stages px=t, 64 channels
      if (valid) {
#pragma unroll
        for (int oct = 0; oct < 8; ++oct)
          *(short8*)(Ab2 + t * 72 + oct * 8) = *(const short8*)(srow + c0 + oct * 8);
      } else {
        short8 z = {0, 0, 0, 0, 0, 0, 0, 0};
#pragma unroll
        for (int oct = 0; oct < 8; ++oct)
          *(short8*)(Ab2 + t * 72 + oct * 8) = z;
      }
      __syncthreads();
#pragma unroll
      for (int ks = 0; ks < 2; ++ks) {
        short8 af[4], bf[2];
#pragma unroll
        for (int mt = 0; mt < 4; ++mt)
          af[mt] = *(short8*)(Ab2 + (w * 64 + mt * 16 + lm) * 72 + ks * 32 + lq * 8);
#pragma unroll
        for (int nt = 0; nt < 2; ++nt)
          bf[nt] = *(short8*)(Bb2 + (nt * 16 + lm) * 72 + ks * 32 + lq * 8);
#pragma unroll
        for (int mt = 0; mt < 4; ++mt)
#pragma unroll
          for (int nt = 0; nt < 2; ++nt)
            acc[mt][nt] = __builtin_amdgcn_mfma_f32_16x16x32_bf16(af[mt], bf[nt], acc[mt][nt], 0, 0, 0);
      }
    }
  }

  // epilogue: per-wave LDS transpose (zone in Ab2), bias+sigmoid, coalesced store
  float* ez = (float*)Ab2 + w * 1088;  // 64*17 floats
#pragma unroll
  for (int nt = 0; nt < 2; ++nt) {
    __syncthreads();
#pragma unroll
    for (int mt = 0; mt < 4; ++mt)
#pragma unroll
      for (int r = 0; r < 4; ++r)
        ez[(mt * 16 + lq * 4 + r) * 17 + lm] = acc[mt][nt][r];
    __syncthreads();
#pragma unroll
    for (int j = 0; j < 16; ++j) {
      int n = nt * 16 + j;
      if (n < 27) {
        float v = ez[l * 17 + j];
        if (n < 18) {
          v += offb[n];
        } else {
          v += modb[n - 18];
          v = 1.f / (1.f + expf(-v));
        }
        om[((size_t)b * 27 + n) * HW + posim0 + w * 64 + l] = v;
      }
    }
  }
}

// ---------------- main deformable conv: MFMA GEMM ----------------
// 576 blocks (XCD-swizzled) x 256 thr. M-tile 64 px, N=256, K = 9 taps x 2x64c.
__global__ __launch_bounds__(256) void k_mfma(const unsigned short* __restrict__ xTb,
                                              const unsigned short* __restrict__ wTt,
                                              const float* __restrict__ bias,
                                              const float* __restrict__ om,
                                              float* __restrict__ out) {
  __shared__ __align__(16) unsigned short Ab[64 * 72];    // 9216 B
  __shared__ __align__(16) unsigned short Bb[256 * 72];   // 36864 B

  int t = threadIdx.x;
  int l = t & 63;
  int w = t >> 6;
  int lm = l & 15, lq = l >> 4;
  int raw = blockIdx.x;
  int bid = (raw & 7) * 72 + (raw >> 3);   // XCD-contiguous M regions
  int pix0 = bid * 64;
  int b = pix0 / HW;
  int posim0 = pix0 % HW;

  int px = t & 63;
  int basegrp = t >> 6;
  int pos = pix0 + px;
  int ho = (pos % HW) / 96, wo = pos % 96;
  const float* omp = om + (size_t)b * 27 * HW + (pos % HW);

  f32x4 acc[4][4];
#pragma unroll
  for (int i = 0; i < 4; ++i)
#pragma unroll
    for (int j = 0; j < 4; ++j)
      acc[i][j] = (f32x4){0.f, 0.f, 0.f, 0.f};

  for (int kpos = 0; kpos < 9; ++kpos) {
    // geometry in registers (4x redundant across threads sharing px)
    float dy = omp[(size_t)(2 * kpos) * HW];
    float dx = omp[(size_t)(2 * kpos + 1) * HW];
    float mk = omp[(size_t)(18 + kpos) * HW];
    float py = (float)(ho - 1 + kpos / 3) + dy;
    float pxf = (float)(wo - 1 + kpos % 3) + dx;
    float fy = floorf(py), fx = floorf(pxf);
    int y0 = (int)fy, x0 = (int)fx;
    float ly = py - fy, lx = pxf - fx;
    float w00 = (1.f - ly) * (1.f - lx), w01 = (1.f - ly) * lx;
    float w10 = ly * (1.f - lx),         w11 = ly * lx;
    bool vy0 = (unsigned)y0 < 96u, vy1 = (unsigned)(y0 + 1) < 96u;
    bool vx0 = (unsigned)x0 < 96u, vx1 = (unsigned)(x0 + 1) < 96u;
    w00 = (vy0 && vx0) ? w00 * mk : 0.f;
    w01 = (vy0 && vx1) ? w01 * mk : 0.f;
    w10 = (vy1 && vx0) ? w10 * mk : 0.f;
    w11 = (vy1 && vx1) ? w11 * mk : 0.f;
    int y0c = min(max(y0, 0), 95), y1c = min(max(y0 + 1, 0), 95);
    int x0c = min(max(x0, 0), 95), x1c = min(max(x0 + 1, 0), 95);
    int ibase = b * HW;
    int o00 = (ibase + y0c * 96 + x0c) * 128;
    int o01 = (ibase + y0c * 96 + x1c) * 128;
    int o10 = (ibase + y1c * 96 + x0c) * 128;
    int o11 = (ibase + y1c * 96 + x1c) * 128;

#pragma unroll
    for (int half = 0; half < 2; ++half) {
      int c0 = half * 64;
      __syncthreads();
      // ---- stage B: 256 n-rows x 64 k, pad 72
      {
        const unsigned short* src = wTt + (size_t)(t >> 3) * 1152 + kpos * 128 + c0 + (t & 7) * 8;
        unsigned short* dst = Bb + (t >> 3) * 72 + (t & 7) * 8;
#pragma unroll
        for (int pp = 0; pp < 8; ++pp)
          *(short8*)(dst + pp * 32 * 72) = *(const short8*)(src + (size_t)pp * 32 * 1152);
      }
      // ---- stage A: sample 64 px x 64 c (bf16 in, fp32 interp, bf16 out)
#pragma unroll
      for (int item = 0; item < 2; ++item) {
        int oct = basegrp + 4 * item;
        int cc = c0 + oct * 8;
        uint4 q00 = *(const uint4*)(xTb + o00 + cc);
        uint4 q01 = *(const uint4*)(xTb + o01 + cc);
        uint4 q10 = *(const uint4*)(xTb + o10 + cc);
        uint4 q11 = *(const uint4*)(xTb + o11 + cc);
        union { short8 v; unsigned short s[8]; } r;
        unsigned qa[4] = {q00.x, q00.y, q00.z, q00.w};
        unsigned qb[4] = {q01.x, q01.y, q01.z, q01.w};
        unsigned qc[4] = {q10.x, q10.y, q10.z, q10.w};
        unsigned qd[4] = {q11.x, q11.y, q11.z, q11.w};
#pragma unroll
        for (int j = 0; j < 4; ++j) {
          float lo = w00 * bflo(qa[j]) + w01 * bflo(qb[j]) + w10 * bflo(qc[j]) + w11 * bflo(qd[j]);
          float hi = w00 * bfhi(qa[j]) + w01 * bfhi(qb[j]) + w10 * bfhi(qc[j]) + w11 * bfhi(qd[j]);
          r.s[2 * j]     = f2bf(lo);
          r.s[2 * j + 1] = f2bf(hi);
        }
        *(short8*)(Ab + px * 72 + oct * 8) = r.v;
      }
      __syncthreads();
      // ---- MFMA
#pragma unroll
      for (int ks = 0; ks < 2; ++ks) {
        short8 af[4], bf[4];
#pragma unroll
        for (int mt = 0; mt < 4; ++mt)
          af[mt] = *(short8*)(Ab + (mt * 16 + lm) * 72 + ks * 32 + lq * 8);
#pragma unroll
        for (int nt = 0; nt < 4; ++nt)
          bf[nt] = *(short8*)(Bb + (w * 64 + nt * 16 + lm) * 72 + ks * 32 + lq * 8);
#pragma unroll
        for (int mt = 0; mt < 4; ++mt)
#pragma unroll
          for (int nt = 0; nt < 4; ++nt)
            acc[mt][nt] = __builtin_amdgcn_mfma_f32_16x16x32_bf16(af[mt], bf[nt], acc[mt][nt], 0, 0, 0);
      }
    }
  }

  // ---- epilogue: per-wave LDS transpose -> coalesced stores
  float bias_v[4];
#pragma unroll
  for (int nt = 0; nt < 4; ++nt) bias_v[nt] = bias[w * 64 + nt * 16 + lm];
  float* ez = (float*)Bb + w * 1088;   // 64*17 floats per wave zone
#pragma unroll
  for (int nt = 0; nt < 4; ++nt) {
    __syncthreads();
#pragma unroll
    for (int mt = 0; mt < 4; ++mt)
#pragma unroll
      for (int r = 0; r < 4; ++r)
        ez[(mt * 16 + lq * 4 + r) * 17 + lm] = acc[mt][nt][r] + bias_v[nt];
    __syncthreads();
    float* ob = out + ((size_t)(b * COUT + w * 64 + nt * 16)) * HW + posim0;
#pragma unroll
    for (int j = 0; j < 16; ++j)
      ob[(size_t)j * HW + l] = ez[l * 17 + j];
  }
}

extern "C" void kernel_launch(void* const* d_in, const int* in_sizes, int n_in,
                              void* d_out, int out_size, void* d_ws, size_t ws_size,
                              hipStream_t stream) {
  const float* x      = (const float*)d_in[0];
  const float* weight = (const float*)d_in[1];
  const float* bias   = (const float*)d_in[2];
  const float* offw   = (const float*)d_in[3];
  const float* offb   = (const float*)d_in[4];
  const float* modw   = (const float*)d_in[5];
  const float* modb   = (const float*)d_in[6];
  float* out = (float*)d_out;
  float* ws = (float*)d_ws;

  float* offmask = ws;                                        // 995328 f
  unsigned short* xTb = (unsigned short*)(ws + 995328);       // 4718592 us (2359296 f)
  unsigned short* wTt = (unsigned short*)(ws + 995328 + 2359296);           // 294912 us
  unsigned short* wAb = (unsigned short*)(ws + 995328 + 2359296 + 147456);  // 36864 us
  // total ws use ~14.2 MB

  k_xtb<<<1152, 256, 0, stream>>>(x, xTb);
  k_wab<<<144, 256, 0, stream>>>(wAb, offw, modw);
  k_wtb<<<1152, 256, 0, stream>>>(wTt, weight);
  k_offconv<<<144, 256, 0, stream>>>(xTb, wAb, offb, modb, offmask);
  k_mfma<<<576, 256, 0, stream>>>(xTb, wTt, bias, offmask, out);
}